// Round 11
// baseline (272.398 us; speedup 1.0000x reference)
//
#include <hip/hip_runtime.h>
#include <stdint.h>

#define BATCH 2
#define SEQ   2048
#define DM    1024
#define NH    16
#define DK    64

#define MEG4 4194304UL
#define MEG1 1048576UL
// ws layout (bf16 element offsets):
//   [0, 4M)    q_ws   (Q proj, PRE-SCALED by 0.125*log2e, [B,H,S,dk])
//   [4M, 8M)   k_ws   (K proj, [B,H,S,dk])
//   [8M, 12M)  vt_ws  (V proj transposed, [B,H,dk,S])
//   [12M,16M)  o_ws   (attn out, [B,S,D])
//   [16M,20M)  staged q ; [20M,24M) k ; [24M,28M) v
//   [28M,29M)  wq ; [29M,30M) wk ; [30M,31M) wv ; [31M,32M) wo
//   [32M + 1024*{0,1,2,3})  bq,bk,bv,bo
#define STAGE_BASE (4 * MEG4)
#define SB         (8 * MEG4)

// 0.125 (1/sqrt(dk)) * log2(e): QK^T lands in exp2 domain directly
#define QSCALE 0.18033688011112042f

typedef __bf16 v8bf __attribute__((ext_vector_type(8)));
typedef float  v4f  __attribute__((ext_vector_type(4)));

// async global->LDS, 16B per lane; LDS dest = wave-uniform base + lane*16
#define GLDS(g, l) __builtin_amdgcn_global_load_lds(                          \
    (const __attribute__((address_space(1))) uint32_t*)(g),                   \
    (__attribute__((address_space(3))) uint32_t*)(l), 16, 0, 0)

static __device__ __forceinline__ float bf2f(uint16_t u) {
    union { uint32_t i; float f; } c; c.i = ((uint32_t)u) << 16; return c.f;
}
static __device__ __forceinline__ uint16_t f2bf(float f) {   // RNE
    union { float f; uint32_t i; } c; c.f = f;
    uint32_t x = c.i;
    return (uint16_t)((x + 0x7fffu + ((x >> 16) & 1u)) >> 16);
}
static __device__ __forceinline__ uint32_t f2bf_pk(float a, float b) {
#if __has_builtin(__builtin_amdgcn_cvt_pk_bf16_f32)
    typedef __bf16 v2bf __attribute__((ext_vector_type(2)));
    union { v2bf v; uint32_t u; } c;
    c.v = __builtin_amdgcn_cvt_pk_bf16_f32(a, b);
    return c.u;
#else
    union { float f; uint32_t i; } ca, cb; ca.f = a; cb.f = b;
    return (ca.i >> 16) | (cb.i & 0xFFFF0000u);
#endif
}
static __device__ __forceinline__ float fast_exp2(float x) {
#if __has_builtin(__builtin_amdgcn_exp2f)
    return __builtin_amdgcn_exp2f(x);
#else
    return __exp2f(x);
#endif
}

// ---------------------------------------------------------------------------
// Inputs are fp32 (confirmed R3). Stage all 11 tensors into ws as bf16.
// ---------------------------------------------------------------------------
__global__ __launch_bounds__(256) void convert_kernel(
    const float* s0, const float* s1, const float* s2, const float* s3,
    const float* s4, const float* s5, const float* s6, const float* s7,
    const float* s8, const float* s9, const float* s10,
    uint16_t* __restrict__ ws)
{
    // z order: q,k,v, wq,bq, wk,bk, wv,bv, wo,bo
    constexpr size_t SZ[11]  = {MEG4, MEG4, MEG4, MEG1, 1024, MEG1, 1024,
                                MEG1, 1024, MEG1, 1024};
    constexpr size_t OFF[11] = {STAGE_BASE, STAGE_BASE + MEG4, STAGE_BASE + 2 * MEG4,
                                7 * MEG4,          SB + 0,
                                7 * MEG4 + MEG1,   SB + 1024,
                                7 * MEG4 + 2*MEG1, SB + 2048,
                                7 * MEG4 + 3*MEG1, SB + 3072};
    const int z = blockIdx.y;
    size_t i0 = ((size_t)blockIdx.x * 256 + threadIdx.x) * 8;
    if (i0 >= SZ[z]) return;
    const float* src;
    switch (z) {
        case 0: src = s0; break;  case 1: src = s1; break;
        case 2: src = s2; break;  case 3: src = s3; break;
        case 4: src = s4; break;  case 5: src = s5; break;
        case 6: src = s6; break;  case 7: src = s7; break;
        case 8: src = s8; break;  case 9: src = s9; break;
        default: src = s10; break;
    }
    const float* s = src + i0;
    uint16_t* dst = ws + OFF[z] + i0;
#pragma unroll
    for (int t = 0; t < 8; t++) dst[t] = f2bf(s[t]);
}

// ---------------------------------------------------------------------------
// gemm_bt core: C[M,N] = (A[M,K] @ W[N,K]^T + bias[N]) * scale.
// 64x128 block tile, BK=64, 4 waves side-by-side in N, 16x16x32 bf16 MFMA,
// global_load_lds width=16 staging, XOR-swizzled LDS (R9: kills the 16-way
// bank conflict of 128B rows; SQ_LDS_BANK_CONFLICT 1.4e7 -> noise).
// mode: 0 -> [B,H,S,dk]; 2 -> [B,H,dk,S]; 3 -> row-major [M,N] fp32 out.
// ---------------------------------------------------------------------------
__device__ __forceinline__ void gemm_core(const uint16_t* __restrict__ A,
                                          const uint16_t* __restrict__ W,
                                          const uint16_t* __restrict__ bias,
                                          void* __restrict__ C,
                                          int m0, int n0, int mode, float scale)
{
    constexpr int N = DM, K = DM;
    __shared__ __align__(16) uint16_t sA[64][64];    // 8 KB, rows = 128 B
    __shared__ __align__(16) uint16_t sB[128][64];   // 16 KB

    const int tid  = threadIdx.x;
    const int lane = tid & 63;
    const int wid  = tid >> 6;
    const int ln15 = lane & 15;
    const int quad = lane >> 4;

    v4f acc[4][2];
    const v4f vzero = {0.f, 0.f, 0.f, 0.f};
#pragma unroll
    for (int i = 0; i < 4; i++)
#pragma unroll
        for (int j = 0; j < 2; j++) acc[i][j] = vzero;

    // staging: 1 KB wave chunk = 8 rows x 8 chunks of 16B; source column
    // chunk = schk ^ srow (XOR swizzle).
    const int srow = lane >> 3;                  // 0..7
    const int schk = lane & 7;                   // 0..7
    const int scol = (schk ^ srow) * 8;          // swizzled source col (elems)
    const int key = ln15 & 7;                    // fragment-read swizzle key

    for (int k0 = 0; k0 < K; k0 += 64) {
#pragma unroll
        for (int c = 0; c < 2; c++) {
            int rA = wid * 16 + c * 8;
            GLDS(&A[(size_t)(m0 + rA + srow) * K + k0 + scol], &sA[rA][0]);
        }
#pragma unroll
        for (int c = 0; c < 4; c++) {
            int rB = wid * 32 + c * 8;
            GLDS(&W[(size_t)(n0 + rB + srow) * K + k0 + scol], &sB[rB][0]);
        }
        __syncthreads();   // vmcnt(0) drain + barrier: tiles ready

#pragma unroll
        for (int s = 0; s < 2; s++) {
            v8bf af[4], bfv[2];
#pragma unroll
            for (int i = 0; i < 4; i++) {
                int pc = (s * 4 + quad) ^ key;   // physical chunk
                af[i] = *(const v8bf*)&sA[i * 16 + ln15][pc * 8];
            }
#pragma unroll
            for (int j = 0; j < 2; j++) {
                int pc = (s * 4 + quad) ^ key;
                bfv[j] = *(const v8bf*)&sB[wid * 32 + j * 16 + ln15][pc * 8];
            }
#pragma unroll
            for (int i = 0; i < 4; i++)
#pragma unroll
                for (int j = 0; j < 2; j++)
                    acc[i][j] = __builtin_amdgcn_mfma_f32_16x16x32_bf16(
                        af[i], bfv[j], acc[i][j], 0, 0, 0);
        }
        __syncthreads();   // all reads done before next iter's async writes
    }

    // C/D layout: col=lane&15, row=quad*4+reg  [verified m89/m91]
#pragma unroll
    for (int i = 0; i < 4; i++) {
#pragma unroll
        for (int j = 0; j < 2; j++) {
#pragma unroll
            for (int r = 0; r < 4; r++) {
                int m = m0 + i * 16 + quad * 4 + r;
                int n = n0 + wid * 32 + j * 16 + ln15;
                float val = (acc[i][j][r] + bf2f(bias[n])) * scale;
                if (mode == 3) {
                    ((float*)C)[(size_t)m * N + n] = val;
                } else {
                    int b = m >> 11, s = m & (SEQ - 1);
                    int h = n >> 6,  d = n & (DK - 1);
                    size_t idx;
                    if (mode == 2)
                        idx = (((size_t)(b * NH + h) * DK + d) * SEQ) + s;
                    else
                        idx = (((size_t)(b * NH + h) * SEQ + s) * DK) + d;
                    ((uint16_t*)C)[idx] = f2bf(val);
                }
            }
        }
    }
}

// ---------------------------------------------------------------------------
// Fused QKV projection: ONE dispatch covering all three GEMMs.
// Grid (x = M-tile 0..63, y = global N-tile 0..23); idx%8 == x%8 (XCD).
// ---------------------------------------------------------------------------
__global__ __launch_bounds__(256) void qkv_proj_kernel(
    const uint16_t* __restrict__ qa_, const uint16_t* __restrict__ ka_,
    const uint16_t* __restrict__ va_,
    const uint16_t* __restrict__ wq, const uint16_t* __restrict__ bq,
    const uint16_t* __restrict__ wk, const uint16_t* __restrict__ bk,
    const uint16_t* __restrict__ wv, const uint16_t* __restrict__ bv,
    uint16_t* __restrict__ qo, uint16_t* __restrict__ ko,
    uint16_t* __restrict__ vto)
{
    const int seg = blockIdx.y >> 3;          // 0=Q, 1=K, 2=V
    const int n0  = (blockIdx.y & 7) * 128;   // within-segment N offset
    const int m0  = blockIdx.x * 64;
    const uint16_t* A  = (seg == 0) ? qa_ : (seg == 1) ? ka_ : va_;
    const uint16_t* W  = (seg == 0) ? wq : (seg == 1) ? wk : wv;
    const uint16_t* Bi = (seg == 0) ? bq : (seg == 1) ? bk : bv;
    uint16_t*       O  = (seg == 0) ? qo : (seg == 1) ? ko : vto;
    gemm_core(A, W, Bi, O, m0, n0, (seg == 2) ? 2 : 0,
              (seg == 0) ? QSCALE : 1.0f);
}

__global__ __launch_bounds__(256) void out_proj_kernel(
    const uint16_t* __restrict__ A, const uint16_t* __restrict__ W,
    const uint16_t* __restrict__ Bi, float* __restrict__ O)
{
    gemm_core(A, W, Bi, O, blockIdx.x * 64, blockIdx.y * 128, 3, 1.0f);
}

// ---------------------------------------------------------------------------
// Flash-style causal attention, work-balanced, max-free softmax, deferred
// row-sum reduction. R10: register prefetch of the next K/V tile with
// __launch_bounds__(256, 2) — LDS caps us at 2 blocks/CU (= 2 waves/EU), so
// the VGPR cap rises to ~256 and the 8 prefetch uint4s fit WITHOUT the
// scratch spill that killed R4 (which had no bounds hint -> 108-VGPR cap).
// XCD swizzle: blockIdx.x = h. Block p handles Q-tile pair (p, 31-p).
// ---------------------------------------------------------------------------
__global__ __launch_bounds__(256, 2) void attn_kernel(
    const uint16_t* __restrict__ Qw, const uint16_t* __restrict__ Kw,
    const uint16_t* __restrict__ VTw, uint16_t* __restrict__ Ow)
{
    __shared__ __align__(16) uint16_t sK[128][72];    // 18432 B
    __shared__ __align__(16) uint16_t sVT[64][136];   // 17408 B
    __shared__ __align__(16) uint16_t sP[128][136];   // 34816 B

    const int tid  = threadIdx.x;
    const int lane = tid & 63;
    const int wid  = tid >> 6;
    const int ln15 = lane & 15;
    const int quad = lane >> 4;
    const int h = blockIdx.x, p = blockIdx.y, b = blockIdx.z;
    const float NEG = -30000.0f;   // exp2(NEG) == 0

    const int qt[2]   = { p, 31 - p };
    const int jmax[2] = { p >> 1, (31 - p) >> 1 };

    const uint16_t* Qb  = Qw  + (size_t)(b * NH + h) * SEQ * DK;
    const uint16_t* Kb  = Kw  + (size_t)(b * NH + h) * SEQ * DK;
    const uint16_t* VTb = VTw + (size_t)(b * NH + h) * DK * SEQ;

    // Q fragments: A[m=lane&15][k=quad*8+j]
    v8bf qa[2][2];
#pragma unroll
    for (int t = 0; t < 2; t++)
#pragma unroll
        for (int ks = 0; ks < 2; ks++)
            qa[t][ks] = *(const v8bf*)&Qb[(size_t)(qt[t] * 64 + wid * 16 + ln15) * DK
                                          + ks * 32 + quad * 8];

    const v4f vzero = {0.f, 0.f, 0.f, 0.f};
    v4f o_acc[2][4];
#pragma unroll
    for (int t = 0; t < 2; t++)
#pragma unroll
        for (int tn = 0; tn < 4; tn++) o_acc[t][tn] = vzero;
    float lrow[2][4];   // per-lane partial row sums (reduced in epilogue)
#pragma unroll
    for (int t = 0; t < 2; t++)
#pragma unroll
        for (int r = 0; r < 4; r++) lrow[t][r] = 0.f;

    // K/V prefetch registers (4+4 uint4 per thread; ~32 VGPR)
    uint4 pk[4], pv[4];
    const int krow = tid >> 3, kcol = (tid & 7) * 8;     // K: [128][64]
    const int vrow = tid >> 4, vcol = (tid & 15) * 8;    // VT: [64][128]
#pragma unroll
    for (int t4 = 0; t4 < 4; t4++) {
        pk[t4] = *(const uint4*)&Kb[(size_t)(krow + t4 * 32) * DK + kcol];
        pv[t4] = *(const uint4*)&VTb[(size_t)(vrow + t4 * 16) * SEQ + vcol];
    }

    for (int j = 0; j <= jmax[1]; j++) {
        __syncthreads();   // prior QK^T sK reads + PV sVT reads done

        // commit prefetched tile j to LDS
#pragma unroll
        for (int t4 = 0; t4 < 4; t4++) {
            *(uint4*)&sK[krow + t4 * 32][kcol]  = pk[t4];
            *(uint4*)&sVT[vrow + t4 * 16][vcol] = pv[t4];
        }
        __syncthreads();

        // issue prefetch of tile j+1 (hides L2/HBM latency behind compute)
        if (j < jmax[1]) {
            const uint16_t* Ksrc = Kb + (size_t)(j + 1) * 128 * DK;
            const uint16_t* Vsrc = VTb + (size_t)(j + 1) * 128;
#pragma unroll
            for (int t4 = 0; t4 < 4; t4++) {
                pk[t4] = *(const uint4*)&Ksrc[(size_t)(krow + t4 * 32) * DK + kcol];
                pv[t4] = *(const uint4*)&Vsrc[(size_t)(vrow + t4 * 16) * SEQ + vcol];
            }
        }

#pragma unroll
        for (int t = 0; t < 2; t++) {
            if (j > jmax[t]) continue;   // block-uniform branch
            v4f sacc[8];
#pragma unroll
            for (int tn = 0; tn < 8; tn++) sacc[tn] = vzero;
#pragma unroll
            for (int tn = 0; tn < 8; tn++) {
                v8bf k0 = *(const v8bf*)&sK[tn * 16 + ln15][quad * 8];
                v8bf k1 = *(const v8bf*)&sK[tn * 16 + ln15][32 + quad * 8];
                sacc[tn] = __builtin_amdgcn_mfma_f32_16x16x32_bf16(
                    qa[t][0], k0, sacc[tn], 0, 0, 0);
                sacc[tn] = __builtin_amdgcn_mfma_f32_16x16x32_bf16(
                    qa[t][1], k1, sacc[tn], 0, 0, 0);
            }
            const bool diag = (j == (qt[t] >> 1));
#pragma unroll
            for (int r = 0; r < 4; r++) {
                int rloc = quad * 4 + r;
                int grow = qt[t] * 64 + wid * 16 + rloc;
                float pe[8];
                float rs = 0.f;
#pragma unroll
                for (int tn = 0; tn < 8; tn++) {
                    float x = sacc[tn][r];
                    if (diag) {
                        int col = j * 128 + tn * 16 + ln15;
                        if (col > grow) x = NEG;
                    }
                    float pvv = fast_exp2(x);
                    pe[tn] = pvv;
                    rs += pvv;
                }
                uint16_t* prow = &sP[t * 64 + wid * 16 + rloc][ln15];
#pragma unroll
                for (int tp = 0; tp < 4; tp++) {
                    uint32_t pk2 = f2bf_pk(pe[2 * tp], pe[2 * tp + 1]);
                    prow[(2 * tp) * 16]     = (uint16_t)pk2;
                    prow[(2 * tp + 1) * 16] = (uint16_t)(pk2 >> 16);
                }
                lrow[t][r] += rs;   // per-lane partial; no shuffles in loop
            }
        }

        // O_t += P_t @ V ; wave reads only its own sP band
#pragma unroll
        for (int t = 0; t < 2; t++) {
            if (j > jmax[t]) continue;
#pragma unroll
            for (int ks = 0; ks < 4; ks++) {
                v8bf pf = *(const v8bf*)&sP[t * 64 + wid * 16 + ln15][ks * 32 + quad * 8];
#pragma unroll
                for (int tn4 = 0; tn4 < 4; tn4++) {
                    v8bf vf = *(const v8bf*)&sVT[tn4 * 16 + ln15][ks * 32 + quad * 8];
                    o_acc[t][tn4] = __builtin_amdgcn_mfma_f32_16x16x32_bf16(
                        pf, vf, o_acc[t][tn4], 0, 0, 0);
                }
            }
        }
    }

    // one-time cross-lane reduction of the deferred row sums
#pragma unroll
    for (int t = 0; t < 2; t++)
#pragma unroll
        for (int r = 0; r < 4; r++)
#pragma unroll
            for (int off = 1; off < 16; off <<= 1)
                lrow[t][r] += __shfl_xor(lrow[t][r], off, 64);

#pragma unroll
    for (int t = 0; t < 2; t++) {
#pragma unroll
        for (int r = 0; r < 4; r++) {
            float inv = 1.f / fmaxf(lrow[t][r], 1e-20f);
            int grow = qt[t] * 64 + wid * 16 + quad * 4 + r;
#pragma unroll
            for (int tn4 = 0; tn4 < 4; tn4++) {
                int d = tn4 * 16 + ln15;
                float val = o_acc[t][tn4][r] * inv;
                Ow[((size_t)b * SEQ + grow) * DM + h * DK + d] = f2bf(val);
            }
        }
    }
}

extern "C" void kernel_launch(void* const* d_in, const int* in_sizes, int n_in,
                              void* d_out, int out_size, void* d_ws, size_t ws_size,
                              hipStream_t stream)
{
    (void)in_sizes; (void)n_in; (void)out_size; (void)ws_size;
    uint16_t* ws = (uint16_t*)d_ws;

    uint16_t* q_ws  = ws;
    uint16_t* k_ws  = ws + MEG4;
    uint16_t* vt_ws = ws + 2 * MEG4;
    uint16_t* o_ws  = ws + 3 * MEG4;
    uint16_t* qs  = ws + STAGE_BASE;
    uint16_t* ks  = ws + STAGE_BASE + MEG4;
    uint16_t* vs  = ws + STAGE_BASE + 2 * MEG4;
    uint16_t* wqs = ws + 7 * MEG4;
    uint16_t* wks = ws + 7 * MEG4 + MEG1;
    uint16_t* wvs = ws + 7 * MEG4 + 2 * MEG1;
    uint16_t* wos = ws + 7 * MEG4 + 3 * MEG1;
    uint16_t* bqs = ws + SB;
    uint16_t* bks = ws + SB + 1024;
    uint16_t* bvs = ws + SB + 2048;
    uint16_t* bos = ws + SB + 3072;

    convert_kernel<<<dim3(2048, 11), 256, 0, stream>>>(
        (const float*)d_in[0], (const float*)d_in[1], (const float*)d_in[2],
        (const float*)d_in[4], (const float*)d_in[5], (const float*)d_in[6],
        (const float*)d_in[7], (const float*)d_in[8], (const float*)d_in[9],
        (const float*)d_in[10], (const float*)d_in[11], ws);

    dim3 blk(256);
    // fused QKV: x = M-tile (XCD swizzle), y = 3 segments x 8 N-tiles
    qkv_proj_kernel<<<dim3(64, 24), blk, 0, stream>>>(
        qs, ks, vs, wqs, bqs, wks, bks, wvs, bvs, q_ws, k_ws, vt_ws);
    attn_kernel<<<dim3(NH, 16, BATCH), blk, 0, stream>>>(
        q_ws, k_ws, vt_ws, o_ws);
    out_proj_kernel<<<dim3(64, 8), blk, 0, stream>>>(o_ws, wos, bos, (float*)d_out);
}

// Round 12
// 227.841 us; speedup vs baseline: 1.1956x; 1.1956x over previous
//
#include <hip/hip_runtime.h>
#include <stdint.h>

#define BATCH 2
#define SEQ   2048
#define DM    1024
#define NH    16
#define DK    64

#define MEG4 4194304UL
#define MEG1 1048576UL
// ws layout (bf16 element offsets):
//   [0, 4M)    q_ws   (Q proj, PRE-SCALED by 0.125*log2e, [B,H,S,dk])
//   [4M, 8M)   k_ws   (K proj, [B,H,S,dk])
//   [8M, 12M)  vt_ws  (V proj transposed, [B,H,dk,S])
//   [12M,16M)  o_ws   (attn out, [B,S,D])
//   [16M,20M)  staged q ; [20M,24M) k ; [24M,28M) v
//   [28M,29M)  wq ; [29M,30M) wk ; [30M,31M) wv ; [31M,32M) wo
//   [32M + 1024*{0,1,2,3})  bq,bk,bv,bo
#define STAGE_BASE (4 * MEG4)
#define SB         (8 * MEG4)

// 0.125 (1/sqrt(dk)) * log2(e): QK^T lands in exp2 domain directly
#define QSCALE 0.18033688011112042f

typedef __bf16 v8bf __attribute__((ext_vector_type(8)));
typedef float  v4f  __attribute__((ext_vector_type(4)));
typedef short  v4s  __attribute__((ext_vector_type(4)));

// async global->LDS, 16B per lane; LDS dest = wave-uniform base + lane*16
#define GLDS(g, l) __builtin_amdgcn_global_load_lds(                          \
    (const __attribute__((address_space(1))) uint32_t*)(g),                   \
    (__attribute__((address_space(3))) uint32_t*)(l), 16, 0, 0)

static __device__ __forceinline__ float bf2f(uint16_t u) {
    union { uint32_t i; float f; } c; c.i = ((uint32_t)u) << 16; return c.f;
}
static __device__ __forceinline__ uint16_t f2bf(float f) {   // RNE
    union { float f; uint32_t i; } c; c.f = f;
    uint32_t x = c.i;
    return (uint16_t)((x + 0x7fffu + ((x >> 16) & 1u)) >> 16);
}
static __device__ __forceinline__ uint32_t f2bf_pk(float a, float b) {
#if __has_builtin(__builtin_amdgcn_cvt_pk_bf16_f32)
    typedef __bf16 v2bf __attribute__((ext_vector_type(2)));
    union { v2bf v; uint32_t u; } c;
    c.v = __builtin_amdgcn_cvt_pk_bf16_f32(a, b);
    return c.u;
#else
    union { float f; uint32_t i; } ca, cb; ca.f = a; cb.f = b;
    return (ca.i >> 16) | (cb.i & 0xFFFF0000u);
#endif
}
static __device__ __forceinline__ float fast_exp2(float x) {
#if __has_builtin(__builtin_amdgcn_exp2f)
    return __builtin_amdgcn_exp2f(x);
#else
    return __exp2f(x);
#endif
}
// 16x16x16 bf16 MFMA (legacy shape, valid on gfx950 per ISA §10).
static __device__ __forceinline__ v4f mfma16_bf16(v4s a, v4s b, v4f c) {
#if __has_builtin(__builtin_amdgcn_mfma_f32_16x16x16_bf16)
    typedef __bf16 v4bf __attribute__((ext_vector_type(4)));
    union { v4s s; v4bf v; } ua, ub; ua.s = a; ub.s = b;
    return __builtin_amdgcn_mfma_f32_16x16x16_bf16(ua.v, ub.v, c, 0, 0, 0);
#else
    return __builtin_amdgcn_mfma_f32_16x16x16bf16_1k(a, b, c, 0, 0, 0);
#endif
}

// ---------------------------------------------------------------------------
// Inputs are fp32 (confirmed R3). Stage all 11 tensors into ws as bf16.
// ---------------------------------------------------------------------------
__global__ __launch_bounds__(256) void convert_kernel(
    const float* s0, const float* s1, const float* s2, const float* s3,
    const float* s4, const float* s5, const float* s6, const float* s7,
    const float* s8, const float* s9, const float* s10,
    uint16_t* __restrict__ ws)
{
    // z order: q,k,v, wq,bq, wk,bk, wv,bv, wo,bo
    constexpr size_t SZ[11]  = {MEG4, MEG4, MEG4, MEG1, 1024, MEG1, 1024,
                                MEG1, 1024, MEG1, 1024};
    constexpr size_t OFF[11] = {STAGE_BASE, STAGE_BASE + MEG4, STAGE_BASE + 2 * MEG4,
                                7 * MEG4,          SB + 0,
                                7 * MEG4 + MEG1,   SB + 1024,
                                7 * MEG4 + 2*MEG1, SB + 2048,
                                7 * MEG4 + 3*MEG1, SB + 3072};
    const int z = blockIdx.y;
    size_t i0 = ((size_t)blockIdx.x * 256 + threadIdx.x) * 8;
    if (i0 >= SZ[z]) return;
    const float* src;
    switch (z) {
        case 0: src = s0; break;  case 1: src = s1; break;
        case 2: src = s2; break;  case 3: src = s3; break;
        case 4: src = s4; break;  case 5: src = s5; break;
        case 6: src = s6; break;  case 7: src = s7; break;
        case 8: src = s8; break;  case 9: src = s9; break;
        default: src = s10; break;
    }
    const float* s = src + i0;
    uint16_t* dst = ws + OFF[z] + i0;
#pragma unroll
    for (int t = 0; t < 8; t++) dst[t] = f2bf(s[t]);
}

// ---------------------------------------------------------------------------
// gemm_bt core: C[M,N] = (A[M,K] @ W[N,K]^T + bias[N]) * scale.
// 64x128 block tile, BK=64, 4 waves side-by-side in N, 16x16x32 bf16 MFMA,
// global_load_lds width=16 staging, XOR-swizzled LDS (R9: kills the 16-way
// bank conflict of 128B rows).
// mode: 0 -> [B,H,S,dk]; 2 -> [B,H,dk,S]; 3 -> row-major [M,N] fp32 out.
// ---------------------------------------------------------------------------
__device__ __forceinline__ void gemm_core(const uint16_t* __restrict__ A,
                                          const uint16_t* __restrict__ W,
                                          const uint16_t* __restrict__ bias,
                                          void* __restrict__ C,
                                          int m0, int n0, int mode, float scale)
{
    constexpr int N = DM, K = DM;
    __shared__ __align__(16) uint16_t sA[64][64];    // 8 KB, rows = 128 B
    __shared__ __align__(16) uint16_t sB[128][64];   // 16 KB

    const int tid  = threadIdx.x;
    const int lane = tid & 63;
    const int wid  = tid >> 6;
    const int ln15 = lane & 15;
    const int quad = lane >> 4;

    v4f acc[4][2];
    const v4f vzero = {0.f, 0.f, 0.f, 0.f};
#pragma unroll
    for (int i = 0; i < 4; i++)
#pragma unroll
        for (int j = 0; j < 2; j++) acc[i][j] = vzero;

    const int srow = lane >> 3;                  // 0..7
    const int schk = lane & 7;                   // 0..7
    const int scol = (schk ^ srow) * 8;          // swizzled source col (elems)
    const int key = ln15 & 7;                    // fragment-read swizzle key

    for (int k0 = 0; k0 < K; k0 += 64) {
#pragma unroll
        for (int c = 0; c < 2; c++) {
            int rA = wid * 16 + c * 8;
            GLDS(&A[(size_t)(m0 + rA + srow) * K + k0 + scol], &sA[rA][0]);
        }
#pragma unroll
        for (int c = 0; c < 4; c++) {
            int rB = wid * 32 + c * 8;
            GLDS(&W[(size_t)(n0 + rB + srow) * K + k0 + scol], &sB[rB][0]);
        }
        __syncthreads();   // vmcnt(0) drain + barrier: tiles ready

#pragma unroll
        for (int s = 0; s < 2; s++) {
            v8bf af[4], bfv[2];
#pragma unroll
            for (int i = 0; i < 4; i++) {
                int pc = (s * 4 + quad) ^ key;   // physical chunk
                af[i] = *(const v8bf*)&sA[i * 16 + ln15][pc * 8];
            }
#pragma unroll
            for (int j = 0; j < 2; j++) {
                int pc = (s * 4 + quad) ^ key;
                bfv[j] = *(const v8bf*)&sB[wid * 32 + j * 16 + ln15][pc * 8];
            }
#pragma unroll
            for (int i = 0; i < 4; i++)
#pragma unroll
                for (int j = 0; j < 2; j++)
                    acc[i][j] = __builtin_amdgcn_mfma_f32_16x16x32_bf16(
                        af[i], bfv[j], acc[i][j], 0, 0, 0);
        }
        __syncthreads();   // all reads done before next iter's async writes
    }

    // C/D layout: col=lane&15, row=quad*4+reg  [verified m89/m91]
#pragma unroll
    for (int i = 0; i < 4; i++) {
#pragma unroll
        for (int j = 0; j < 2; j++) {
#pragma unroll
            for (int r = 0; r < 4; r++) {
                int m = m0 + i * 16 + quad * 4 + r;
                int n = n0 + wid * 32 + j * 16 + ln15;
                float val = (acc[i][j][r] + bf2f(bias[n])) * scale;
                if (mode == 3) {
                    ((float*)C)[(size_t)m * N + n] = val;
                } else {
                    int b = m >> 11, s = m & (SEQ - 1);
                    int h = n >> 6,  d = n & (DK - 1);
                    size_t idx;
                    if (mode == 2)
                        idx = (((size_t)(b * NH + h) * DK + d) * SEQ) + s;
                    else
                        idx = (((size_t)(b * NH + h) * SEQ + s) * DK) + d;
                    ((uint16_t*)C)[idx] = f2bf(val);
                }
            }
        }
    }
}

// ---------------------------------------------------------------------------
// Fused QKV projection: ONE dispatch covering all three GEMMs.
// Grid (x = M-tile 0..63, y = global N-tile 0..23); idx%8 == x%8 (XCD).
// ---------------------------------------------------------------------------
__global__ __launch_bounds__(256) void qkv_proj_kernel(
    const uint16_t* __restrict__ qa_, const uint16_t* __restrict__ ka_,
    const uint16_t* __restrict__ va_,
    const uint16_t* __restrict__ wq, const uint16_t* __restrict__ bq,
    const uint16_t* __restrict__ wk, const uint16_t* __restrict__ bk,
    const uint16_t* __restrict__ wv, const uint16_t* __restrict__ bv,
    uint16_t* __restrict__ qo, uint16_t* __restrict__ ko,
    uint16_t* __restrict__ vto)
{
    const int seg = blockIdx.y >> 3;          // 0=Q, 1=K, 2=V
    const int n0  = (blockIdx.y & 7) * 128;   // within-segment N offset
    const int m0  = blockIdx.x * 64;
    const uint16_t* A  = (seg == 0) ? qa_ : (seg == 1) ? ka_ : va_;
    const uint16_t* W  = (seg == 0) ? wq : (seg == 1) ? wk : wv;
    const uint16_t* Bi = (seg == 0) ? bq : (seg == 1) ? bk : bv;
    uint16_t*       O  = (seg == 0) ? qo : (seg == 1) ? ko : vto;
    gemm_core(A, W, Bi, O, m0, n0, (seg == 2) ? 2 : 0,
              (seg == 0) ? QSCALE : 1.0f);
}

__global__ __launch_bounds__(256) void out_proj_kernel(
    const uint16_t* __restrict__ A, const uint16_t* __restrict__ W,
    const uint16_t* __restrict__ Bi, float* __restrict__ O)
{
    gemm_core(A, W, Bi, O, blockIdx.x * 64, blockIdx.y * 128, 3, 1.0f);
}

// ---------------------------------------------------------------------------
// Flash-style causal attention, R11 restructure: NO sP LDS round-trip.
// Compute S^T = K @ Q^T (A=K, B=Q) so the C-layout per lane is
// [key=quad*4+r][qrow=ln15] — exactly the B-operand layout of
// mfma_f32_16x16x16_bf16. P^T feeds the PV MFMA (O^T = V^T @ P^T, A=V^T
// from the [dk][S] LDS tile) straight from registers.
//   - LDS 70.6 -> 35.8 KB => 4 blocks/CU (was 2): doubles latency hiding.
//   - removes P pack/store/reload + one barrier per K-tile.
//   - row sum is one scalar/lane (qrow=ln15); 2 shuffles in epilogue.
// R11 lesson: register prefetch of K/V spills to scratch regardless of
// launch_bounds (R4, R11: WRITE_SIZE 186/100 MB). Plain staging only.
// XCD swizzle: blockIdx.x = h. Block p handles Q-tile pair (p, 31-p).
// ---------------------------------------------------------------------------
__global__ __launch_bounds__(256) void attn_kernel(
    const uint16_t* __restrict__ Qw, const uint16_t* __restrict__ Kw,
    const uint16_t* __restrict__ VTw, uint16_t* __restrict__ Ow)
{
    __shared__ __align__(16) uint16_t sK[128][72];    // 18432 B
    __shared__ __align__(16) uint16_t sVT[64][136];   // 17408 B

    const int tid  = threadIdx.x;
    const int lane = tid & 63;
    const int wid  = tid >> 6;
    const int ln15 = lane & 15;
    const int quad = lane >> 4;
    const int h = blockIdx.x, p = blockIdx.y, b = blockIdx.z;
    const float NEG = -30000.0f;   // exp2(NEG) == 0

    const int qt[2]   = { p, 31 - p };
    const int jmax[2] = { p >> 1, (31 - p) >> 1 };

    const uint16_t* Qb  = Qw  + (size_t)(b * NH + h) * SEQ * DK;
    const uint16_t* Kb  = Kw  + (size_t)(b * NH + h) * SEQ * DK;
    const uint16_t* VTb = VTw + (size_t)(b * NH + h) * DK * SEQ;

    // Q fragments (B-operand: B[n=qrow=ln15][k=d=quad*8+j])
    v8bf qb[2][2];
#pragma unroll
    for (int t = 0; t < 2; t++)
#pragma unroll
        for (int ks = 0; ks < 2; ks++)
            qb[t][ks] = *(const v8bf*)&Qb[(size_t)(qt[t] * 64 + wid * 16 + ln15) * DK
                                          + ks * 32 + quad * 8];

    const v4f vzero = {0.f, 0.f, 0.f, 0.f};
    // O^T accumulators: [tile][d-group]; C layout col=qrow=ln15, row=d off
    v4f oT[2][4];
#pragma unroll
    for (int t = 0; t < 2; t++)
#pragma unroll
        for (int dm = 0; dm < 4; dm++) oT[t][dm] = vzero;
    float lrow[2] = {0.f, 0.f};   // per-lane (qrow=ln15) partial row sums

    for (int j = 0; j <= jmax[1]; j++) {
        __syncthreads();   // prior S^T sK reads + PV sVT reads done

        const uint16_t* Ksrc = Kb + (size_t)j * 128 * DK;
#pragma unroll
        for (int t4 = 0; t4 < 4; t4++) {
            int s = tid + t4 * 256;
            int row = s >> 3, cs = (s & 7) * 8;
            *(uint4*)&sK[row][cs] = *(const uint4*)&Ksrc[(size_t)row * DK + cs];
        }
#pragma unroll
        for (int t4 = 0; t4 < 4; t4++) {
            int s = tid + t4 * 256;
            int row = s >> 4, cs = (s & 15) * 8;
            *(uint4*)&sVT[row][cs] =
                *(const uint4*)&VTb[(size_t)row * SEQ + j * 128 + cs];
        }
        __syncthreads();

#pragma unroll
        for (int t = 0; t < 2; t++) {
            if (j > jmax[t]) continue;   // block-uniform branch

            // S^T = K @ Q^T : wave covers 128 keys x its 16 qrows
            v4f st[8];
#pragma unroll
            for (int tn = 0; tn < 8; tn++) st[tn] = vzero;
#pragma unroll
            for (int tn = 0; tn < 8; tn++) {
                v8bf k0 = *(const v8bf*)&sK[tn * 16 + ln15][quad * 8];
                v8bf k1 = *(const v8bf*)&sK[tn * 16 + ln15][32 + quad * 8];
                st[tn] = __builtin_amdgcn_mfma_f32_16x16x32_bf16(
                    k0, qb[t][0], st[tn], 0, 0, 0);
                st[tn] = __builtin_amdgcn_mfma_f32_16x16x32_bf16(
                    k1, qb[t][1], st[tn], 0, 0, 0);
            }

            const bool diag = (j == (qt[t] >> 1));
            const int qrow = qt[t] * 64 + wid * 16 + ln15;
            v4s pfrag[8];
#pragma unroll
            for (int tn = 0; tn < 8; tn++) {
                float pe[4];
#pragma unroll
                for (int r = 0; r < 4; r++) {
                    float x = st[tn][r];
                    if (diag) {
                        int keyg = j * 128 + tn * 16 + quad * 4 + r;
                        if (keyg > qrow) x = NEG;
                    }
                    pe[r] = fast_exp2(x);
                    lrow[t] += pe[r];
                }
                union { uint32_t u[2]; v4s s; } c;
                c.u[0] = f2bf_pk(pe[0], pe[1]);
                c.u[1] = f2bf_pk(pe[2], pe[3]);
                pfrag[tn] = c.s;
            }

            // O^T += V^T @ P^T : A[m=d=ln15][k=key=quad*4+j] from sVT,
            // B = pfrag (register-resident), 16x16x16 MFMA.
#pragma unroll
            for (int dm = 0; dm < 4; dm++) {
#pragma unroll
                for (int tn = 0; tn < 8; tn++) {
                    union { uint32_t u[2]; v4s s; } va;
                    const uint32_t* vp = (const uint32_t*)
                        &sVT[dm * 16 + ln15][tn * 16 + quad * 4];
                    va.u[0] = vp[0]; va.u[1] = vp[1];
                    oT[t][dm] = mfma16_bf16(va.s, pfrag[tn], oT[t][dm]);
                }
            }
        }
    }

    // reduce row sums across the 4 quads (same ln15 holds same qrow)
#pragma unroll
    for (int t = 0; t < 2; t++) {
        lrow[t] += __shfl_xor(lrow[t], 16, 64);
        lrow[t] += __shfl_xor(lrow[t], 32, 64);
    }

    // epilogue: O^T layout col=qrow=ln15, row=quad*4+r = d offset in dm*16
#pragma unroll
    for (int t = 0; t < 2; t++) {
        float inv = 1.f / fmaxf(lrow[t], 1e-20f);
        int grow = qt[t] * 64 + wid * 16 + ln15;
#pragma unroll
        for (int dm = 0; dm < 4; dm++) {
#pragma unroll
            for (int r = 0; r < 4; r++) {
                int d = dm * 16 + quad * 4 + r;
                Ow[((size_t)b * SEQ + grow) * DM + h * DK + d] =
                    f2bf(oT[t][dm][r] * inv);
            }
        }
    }
}

extern "C" void kernel_launch(void* const* d_in, const int* in_sizes, int n_in,
                              void* d_out, int out_size, void* d_ws, size_t ws_size,
                              hipStream_t stream)
{
    (void)in_sizes; (void)n_in; (void)out_size; (void)ws_size;
    uint16_t* ws = (uint16_t*)d_ws;

    uint16_t* q_ws  = ws;
    uint16_t* k_ws  = ws + MEG4;
    uint16_t* vt_ws = ws + 2 * MEG4;
    uint16_t* o_ws  = ws + 3 * MEG4;
    uint16_t* qs  = ws + STAGE_BASE;
    uint16_t* ks  = ws + STAGE_BASE + MEG4;
    uint16_t* vs  = ws + STAGE_BASE + 2 * MEG4;
    uint16_t* wqs = ws + 7 * MEG4;
    uint16_t* wks = ws + 7 * MEG4 + MEG1;
    uint16_t* wvs = ws + 7 * MEG4 + 2 * MEG1;
    uint16_t* wos = ws + 7 * MEG4 + 3 * MEG1;
    uint16_t* bqs = ws + SB;
    uint16_t* bks = ws + SB + 1024;
    uint16_t* bvs = ws + SB + 2048;
    uint16_t* bos = ws + SB + 3072;

    convert_kernel<<<dim3(2048, 11), 256, 0, stream>>>(
        (const float*)d_in[0], (const float*)d_in[1], (const float*)d_in[2],
        (const float*)d_in[4], (const float*)d_in[5], (const float*)d_in[6],
        (const float*)d_in[7], (const float*)d_in[8], (const float*)d_in[9],
        (const float*)d_in[10], (const float*)d_in[11], ws);

    dim3 blk(256);
    // fused QKV: x = M-tile (XCD swizzle), y = 3 segments x 8 N-tiles
    qkv_proj_kernel<<<dim3(64, 24), blk, 0, stream>>>(
        qs, ks, vs, wqs, bqs, wks, bks, wvs, bvs, q_ws, k_ws, vt_ws);
    attn_kernel<<<dim3(NH, 16, BATCH), blk, 0, stream>>>(
        q_ws, k_ws, vt_ws, o_ws);
    out_proj_kernel<<<dim3(64, 8), blk, 0, stream>>>(o_ws, wos, bos, (float*)d_out);
}